// Round 3
// baseline (112.415 us; speedup 1.0000x reference)
//
#include <hip/hip_runtime.h>
#include <math.h>

#define IMG_H 512
#define IMG_W 512
#define NB 9

// Block = one cell-row of one image: 64 cells (cx=0..63) x 4 row-pair threads.
// Grid  = 32 images x 64 cell-rows = 2048 blocks of 256.
// Thread (cx, rp) computes output rows h0=cy*8+rp*2 .. h0+1 of its cell.
//
// CORRECTNESS MODEL (do not change): the harness "np" reference is a
// dtype-faithful float32 port. Per-pixel chain is bit-exact:
//   gray  = ((c0+c1)+c2)/3.0f      (IEEE fp32 div)
//   gx,gy = Sobel, tap-lexicographic order, +-1/+-2 (exact multiplies)
//   phase = (float)atan2(fp64)     (correctly-rounded fp32 atan2)
//   pb    = phase / (float)pi * 9  (two fp32 roundings)
//   lo/hi = floored mod 9 of floor/ceil
// Bin accumulation is value-continuous: per-thread private LDS slots via
// ds_add_f32 (no races -> deterministic), fixed-order 4-way reduce.
__global__ __launch_bounds__(256) void hog_kernel(const float* __restrict__ x,
                                                  float* __restrict__ out) {
    __shared__ float sbins[256 * NB];   // 9216 B; stride 9 per thread = odd -> bank-conflict-free

    const int t  = threadIdx.x;
#pragma unroll
    for (int b = 0; b < NB; b++) sbins[t * NB + b] = 0.0f;   // own slots only

    const int n  = blockIdx.x >> 6;     // image
    const int cy = blockIdx.x & 63;     // cell row
    const int cx = t & 63;              // cell col (consecutive lanes -> consecutive cells)
    const int rp = t >> 6;              // row-pair 0..3
    const int h0 = cy * 8 + rp * 2;     // first output row of this thread
    const int w0 = cx * 8;
    const float* xn = x + (size_t)n * 3 * IMG_H * IMG_W;

    // gray rows h0-1 .. h0+2 (4 rows x 10 cols), all static indexing
    float rowbuf[4][10];

#define LOAD_ROW(HROW, SLOT)                                                     \
    {                                                                            \
        const int hh_ = (HROW);                                                  \
        if (hh_ < 0 || hh_ >= IMG_H) {                                           \
            _Pragma("unroll") for (int i_ = 0; i_ < 10; i_++) rowbuf[SLOT][i_] = 0.0f; \
        } else {                                                                 \
            const float* p_ = xn + (size_t)hh_ * IMG_W;                          \
            _Pragma("unroll") for (int i_ = 0; i_ < 10; i_++) {                  \
                const int ww_ = w0 - 1 + i_;                                     \
                if (ww_ < 0 || ww_ >= IMG_W) {                                   \
                    rowbuf[SLOT][i_] = 0.0f;                                     \
                } else {                                                         \
                    float a_ = p_[ww_];                                          \
                    float b_ = p_[IMG_H * IMG_W + ww_];                          \
                    float c_ = p_[2 * IMG_H * IMG_W + ww_];                      \
                    rowbuf[SLOT][i_] = ((a_ + b_) + c_) / 3.0f;                  \
                }                                                                \
            }                                                                    \
        }                                                                        \
    }

#pragma unroll
    for (int k = 0; k < 4; k++) LOAD_ROW(h0 - 1 + k, k)
#undef LOAD_ROW

    float* mybins = &sbins[t * NB];

#pragma unroll
    for (int hy = 0; hy < 2; hy++) {
#pragma unroll
        for (int j = 0; j < 8; j++) {
            const float tl = rowbuf[hy][j],     tc = rowbuf[hy][j + 1],     tr = rowbuf[hy][j + 2];
            const float ml = rowbuf[hy + 1][j],                             mr = rowbuf[hy + 1][j + 2];
            const float bl = rowbuf[hy + 2][j], bc = rowbuf[hy + 2][j + 1], br = rowbuf[hy + 2][j + 2];

            // cross-correlation, tap-lexicographic addition order, exact mults
            const float gx = ((((tl - tr) + 2.0f * ml) - 2.0f * mr) + bl) - br;
            const float gy = ((((tl + 2.0f * tc) + tr) - bl) - 2.0f * bc) - br;

            const float nrm = sqrtf(gx * gx + gy * gy);

            // correctly-rounded fp32 atan2 via fp64 (matches numpy f32 arctan2)
            const float ph  = (float)atan2((double)gx, (double)gy);
            const float pbf = ph / (float)M_PI * 9.0f;

            int lo = (int)floorf(pbf) % NB; if (lo < 0) lo += NB;   // floored mod
            int hi = (int)ceilf(pbf)  % NB; if (hi < 0) hi += NB;

            // private slots -> ds_add_f32, no race, deterministic
            atomicAdd(&mybins[lo], nrm);
            atomicAdd(&mybins[hi], 1.0f - nrm);
        }
    }

    __syncthreads();

    // reduce 4 row-pair partials per (cell,bin); 576 outputs, fixed order.
    // idx = b*64 + cc  -> consecutive threads write consecutive cx: coalesced.
    for (int idx = t; idx < NB * 64; idx += 256) {
        const int b  = idx >> 6;
        const int cc = idx & 63;
        const float s = ((sbins[cc * NB + b] + sbins[(cc + 64) * NB + b])
                         + sbins[(cc + 128) * NB + b]) + sbins[(cc + 192) * NB + b];
        out[((size_t)n * NB + b) * 4096 + (size_t)cy * 64 + cc] = s * (1.0f / 64.0f);
    }
}

extern "C" void kernel_launch(void* const* d_in, const int* in_sizes, int n_in,
                              void* d_out, int out_size, void* d_ws, size_t ws_size,
                              hipStream_t stream) {
    const float* x = (const float*)d_in[0];
    float* out = (float*)d_out;
    // 32 images x 64 cell-rows = 2048 blocks, 256 threads (64 cells x 4 row-pairs)
    hog_kernel<<<2048, 256, 0, stream>>>(x, out);
}

// Round 4
// 103.858 us; speedup vs baseline: 1.0824x; 1.0824x over previous
//
#include <hip/hip_runtime.h>
#include <math.h>

#define IMG_H 512
#define IMG_W 512
#define NB 9
#define GSTRIDE 516   // 514 cols used (idx 0..513) + 2 pad floats

// Block = one 8-row band of one image (grid = 32 images x 64 bands, 256 thr).
// Stage gray rows h0-1..h0+8 in LDS (coalesced float2 loads), then thread t
// computes cols {2t, 2t+1} x 8 rows with a rolling 3-row register window.
//
// CORRECTNESS MODEL (do not change): harness "np" ref is a float32 port.
// Decision chain must be bit-exact:
//   gray  = ((c0+c1)+c2)/3.0f            (IEEE fp32 div)
//   gx,gy = Sobel, tap-lex order, +-1/+-2 (exact multiplies)
//   phase = (float)atan2(fp64), pb = phase/(float)pi*9, floored mod 9
// Hot path uses a fast fp32 atan2 (err ~4e-5 in pb units) ONLY to decide;
// when pb is within 2.5e-4 of an integer (incl. all 0/NaN edge cases) we
// re-run the exact fp64 reference chain. Outside the guard both chains
// provably give the same floor/ceil.
__global__ __launch_bounds__(256) void hog_kernel(const float* __restrict__ x,
                                                  float* __restrict__ out) {
    __shared__ float sgray[10 * GSTRIDE];   // 20640 B
    __shared__ float sbins[256 * NB];       //  9216 B  (stride 9 = odd -> conflict-free)

    const int t  = threadIdx.x;
    const int n  = blockIdx.x >> 6;     // image
    const int cy = blockIdx.x & 63;     // band / cell row
    const int h0 = cy * 8;
    const float* xn = x + (size_t)n * 3 * IMG_H * IMG_W;

#pragma unroll
    for (int b = 0; b < NB; b++) sbins[t * NB + b] = 0.0f;   // own slots only

    // ---- stage gray band: rows h0-1 .. h0+8, col c -> LDS idx c+1 ----
    for (int r = 0; r < 10; r++) {
        const int h = h0 - 1 + r;
        float g0 = 0.0f, g1 = 0.0f;
        if (h >= 0 && h < IMG_H) {
            const float* p = xn + (size_t)h * IMG_W + 2 * t;
            const float2 a = *(const float2*)(p);
            const float2 b = *(const float2*)(p + IMG_H * IMG_W);
            const float2 c = *(const float2*)(p + 2 * IMG_H * IMG_W);
            g0 = ((a.x + b.x) + c.x) / 3.0f;
            g1 = ((a.y + b.y) + c.y) / 3.0f;
        }
        sgray[r * GSTRIDE + 2 * t + 1] = g0;
        sgray[r * GSTRIDE + 2 * t + 2] = g1;
        if (t < 2) sgray[r * GSTRIDE + t * 513] = 0.0f;   // borders idx 0, 513
    }
    __syncthreads();

    float* mybins = &sbins[t * NB];
    const int w0 = 2 * t;   // window idx w0..w0+3 per row covers cols 2t,2t+1

    float ra[4], rb[4], rc[4];
#pragma unroll
    for (int i = 0; i < 4; i++) ra[i] = sgray[0 * GSTRIDE + w0 + i];
#pragma unroll
    for (int i = 0; i < 4; i++) rb[i] = sgray[1 * GSTRIDE + w0 + i];

#pragma unroll
    for (int hy = 0; hy < 8; hy++) {
#pragma unroll
        for (int i = 0; i < 4; i++) rc[i] = sgray[(hy + 2) * GSTRIDE + w0 + i];

#pragma unroll
        for (int p = 0; p < 2; p++) {
            const float tl = ra[p], tc = ra[p + 1], tr = ra[p + 2];
            const float ml = rb[p],                 mr = rb[p + 2];
            const float bl = rc[p], bc = rc[p + 1], br = rc[p + 2];

            // exact ref arithmetic (contraction-safe: all multiplies exact)
            const float gx = ((((tl - tr) + 2.0f * ml) - 2.0f * mr) + bl) - br;
            const float gy = ((((tl + 2.0f * tc) + tr) - bl) - 2.0f * bc) - br;
            const float nrm = sqrtf(gx * gx + gy * gy);

            // ---- fast fp32 atan2 classifier ----
            const float fa = fabsf(gx), fb = fabsf(gy);
            const float mn = fminf(fa, fb), mx = fmaxf(fa, fb);
            float rcpmx;
            asm("v_rcp_f32 %0, %1" : "=v"(rcpmx) : "v"(mx));
            const float tt = mn * rcpmx;            // mx==0 -> NaN -> slow path
            const float ss = tt * tt;
            float po = fmaf(ss, -0.0117212f, 0.05265332f);
            po = fmaf(ss, po, -0.11643287f);
            po = fmaf(ss, po, 0.19354346f);
            po = fmaf(ss, po, -0.33262347f);
            po = fmaf(ss, po, 0.99997726f);
            float th = tt * po;                      // atan(min/max) in [0,pi/4+eps]
            if (fa > fb) th = 1.57079632679489662f - th;
            if (gy < 0.0f) th = 3.14159265358979324f - th;
            if (gx < 0.0f) th = -th;
            const float pbh  = th * 2.86478897565412f;   // *9/pi
            const float fl   = floorf(pbh);
            const float frac = pbh - fl;
            const float dist = fminf(frac, 1.0f - frac);

            int lo, hi;
            if (dist > 2.5e-4f) {                   // NaN -> false -> slow
                lo = (int)fl; if (lo < 0) lo += NB; // fl in [-9,8], floored mod
                hi = lo + 1;  if (hi == NB) hi = 0;
            } else {
                // exact reference chain (bit-identical to rounds 2/3)
                const float ph  = (float)atan2((double)gx, (double)gy);
                const float pbf = ph / (float)M_PI * 9.0f;
                lo = (int)floorf(pbf) % NB; if (lo < 0) lo += NB;
                hi = (int)ceilf(pbf)  % NB; if (hi < 0) hi += NB;
            }

            atomicAdd(&mybins[lo], nrm);            // private slot: ds_add, no race
            atomicAdd(&mybins[hi], 1.0f - nrm);
        }
#pragma unroll
        for (int i = 0; i < 4; i++) { ra[i] = rb[i]; rb[i] = rc[i]; }
    }

    __syncthreads();

    // cell cc gathers threads 4cc..4cc+3; fixed-order reduce; coalesced store
    for (int idx = t; idx < NB * 64; idx += 256) {
        const int b  = idx >> 6;
        const int cc = idx & 63;
        const int base = 4 * cc * NB + b;
        const float s = ((sbins[base] + sbins[base + NB])
                         + sbins[base + 2 * NB]) + sbins[base + 3 * NB];
        out[((size_t)n * NB + b) * 4096 + (size_t)cy * 64 + cc] = s * (1.0f / 64.0f);
    }
}

extern "C" void kernel_launch(void* const* d_in, const int* in_sizes, int n_in,
                              void* d_out, int out_size, void* d_ws, size_t ws_size,
                              hipStream_t stream) {
    const float* x = (const float*)d_in[0];
    float* out = (float*)d_out;
    hog_kernel<<<2048, 256, 0, stream>>>(x, out);
}

// Round 5
// 53.140 us; speedup vs baseline: 2.1155x; 1.9544x over previous
//
#include <hip/hip_runtime.h>
#include <math.h>

#define IMG_H 512
#define IMG_W 512
#define NB 9
#define GSTRIDE 516   // 514 used (0..513) + pad

// ---------------- Kernel 1: gray = mean(channels) ----------------
// Pure streaming: 100.6 MB read + 33.5 MB write. Bit-exact ((a+b)+c)/3.0f.
__global__ __launch_bounds__(256) void gray_kernel(const float* __restrict__ x,
                                                   float* __restrict__ g) {
    const int idx = blockIdx.x * 256 + threadIdx.x;   // float4 idx, 0..2097151
    const int n   = idx >> 16;                        // 65536 float4 per image
    const int rem = idx & 65535;
    const float4* p = (const float4*)(x + (size_t)n * 3 * 262144) + rem;
    const float4 a = p[0];
    const float4 b = p[65536];
    const float4 c = p[131072];
    float4 o;
    o.x = ((a.x + b.x) + c.x) / 3.0f;
    o.y = ((a.y + b.y) + c.y) / 3.0f;
    o.z = ((a.z + b.z) + c.z) / 3.0f;
    o.w = ((a.w + b.w) + c.w) / 3.0f;
    ((float4*)g)[idx] = o;
}

// ---------------- Kernel 2: Sobel + binning + 8x8 pool ----------------
// Block = one 8-row band (grid 32x64). Stage gray rows h0-1..h0+8 in LDS via
// float4; thread t computes cols {2t,2t+1} x 8 rows; bins in REGISTERS with
// static-index cndmask accumulate; LDS reused for the fixed-order reduce.
//
// CORRECTNESS MODEL (do not change): decision chain bit-exact vs the fp32 ref:
// gray ((c0+c1)+c2)/3.0f ; Sobel tap-lex order (+-1/+-2 exact) ;
// fast fp32 atan2 classifier, fp64 exact fallback within 2.5e-4 of integer pb.
__global__ __launch_bounds__(256) void hog2_kernel(const float* __restrict__ g,
                                                   float* __restrict__ out) {
    __shared__ float sgray[10 * GSTRIDE];   // 20640 B; reused as reduce buffer

    const int t  = threadIdx.x;
    const int n  = blockIdx.x >> 6;
    const int cy = blockIdx.x & 63;
    const int h0 = cy * 8;
    const float* gn = g + (size_t)n * 262144;

    if (t < 20) sgray[(t >> 1) * GSTRIDE + (t & 1) * 513] = 0.0f;  // borders
#pragma unroll
    for (int k = 0; k < 5; k++) {            // 10 rows x 128 float4
        const int i4 = t + k * 256;
        const int r  = i4 >> 7;
        const int c4 = i4 & 127;
        const int h  = h0 - 1 + r;
        float4 v = make_float4(0.0f, 0.0f, 0.0f, 0.0f);
        if (h >= 0 && h < IMG_H) v = *((const float4*)(gn + (size_t)h * IMG_W) + c4);
        float* dst = &sgray[r * GSTRIDE + c4 * 4 + 1];
        dst[0] = v.x; dst[1] = v.y; dst[2] = v.z; dst[3] = v.w;
    }
    __syncthreads();

    float bins[NB];
#pragma unroll
    for (int b = 0; b < NB; b++) bins[b] = 0.0f;

    const int w0 = 2 * t;
    float ra[4], rb[4], rc[4];
#pragma unroll
    for (int i = 0; i < 4; i++) ra[i] = sgray[0 * GSTRIDE + w0 + i];
#pragma unroll
    for (int i = 0; i < 4; i++) rb[i] = sgray[1 * GSTRIDE + w0 + i];

#pragma unroll
    for (int hy = 0; hy < 8; hy++) {
#pragma unroll
        for (int i = 0; i < 4; i++) rc[i] = sgray[(hy + 2) * GSTRIDE + w0 + i];

#pragma unroll
        for (int p = 0; p < 2; p++) {
            const float tl = ra[p], tc = ra[p + 1], tr = ra[p + 2];
            const float ml = rb[p],                 mr = rb[p + 2];
            const float bl = rc[p], bc = rc[p + 1], br = rc[p + 2];

            const float gx = ((((tl - tr) + 2.0f * ml) - 2.0f * mr) + bl) - br;
            const float gy = ((((tl + 2.0f * tc) + tr) - bl) - 2.0f * bc) - br;
            const float nrm = sqrtf(gx * gx + gy * gy);

            // fast fp32 atan2 classifier
            const float fa = fabsf(gx), fb = fabsf(gy);
            const float mn = fminf(fa, fb), mx = fmaxf(fa, fb);
            float rcpmx;
            asm("v_rcp_f32 %0, %1" : "=v"(rcpmx) : "v"(mx));
            const float tt = mn * rcpmx;            // mx==0 -> NaN -> slow path
            const float ss = tt * tt;
            float po = fmaf(ss, -0.0117212f, 0.05265332f);
            po = fmaf(ss, po, -0.11643287f);
            po = fmaf(ss, po, 0.19354346f);
            po = fmaf(ss, po, -0.33262347f);
            po = fmaf(ss, po, 0.99997726f);
            float th = tt * po;
            if (fa > fb) th = 1.57079632679489662f - th;
            if (gy < 0.0f) th = 3.14159265358979324f - th;
            if (gx < 0.0f) th = -th;
            const float pbh  = th * 2.86478897565412f;   // *9/pi
            const float fl   = floorf(pbh);
            const float frac = pbh - fl;
            const float dist = fminf(frac, 1.0f - frac);

            int lo, hi;
            if (dist > 2.5e-4f) {                   // NaN -> false -> slow
                lo = (int)fl; if (lo < 0) lo += NB;
                hi = lo + 1;  if (hi == NB) hi = 0;
            } else {
                // exact reference chain (bit-identical to rounds 2-4)
                const float ph  = (float)atan2((double)gx, (double)gy);
                const float pbf = ph / (float)M_PI * 9.0f;
                lo = (int)floorf(pbf) % NB; if (lo < 0) lo += NB;
                hi = (int)ceilf(pbf)  % NB; if (hi < 0) hi += NB;
            }

            const float om = 1.0f - nrm;
#pragma unroll
            for (int b = 0; b < NB; b++)
                bins[b] += ((b == lo) ? nrm : 0.0f) + ((b == hi) ? om : 0.0f);
        }
#pragma unroll
        for (int i = 0; i < 4; i++) { ra[i] = rb[i]; rb[i] = rc[i]; }
    }

    __syncthreads();                         // done reading sgray as gray
    float* sred = sgray;                     // alias: needs 2304 < 5160 floats
#pragma unroll
    for (int b = 0; b < NB; b++) sred[t * NB + b] = bins[b];
    __syncthreads();

    // cell cc gathers threads 4cc..4cc+3 (cols 8cc..8cc+7); fixed order
    for (int idx = t; idx < NB * 64; idx += 256) {
        const int b  = idx >> 6;
        const int cc = idx & 63;
        const int base = 4 * cc * NB + b;
        const float s = ((sred[base] + sred[base + NB])
                         + sred[base + 2 * NB]) + sred[base + 3 * NB];
        out[((size_t)n * NB + b) * 4096 + (size_t)cy * 64 + cc] = s * (1.0f / 64.0f);
    }
}

// ---------------- Fallback (proven round-4 kernel) if ws too small ----------
__global__ __launch_bounds__(256) void hog_fb_kernel(const float* __restrict__ x,
                                                     float* __restrict__ out) {
    __shared__ float sgray[10 * GSTRIDE];
    __shared__ float sbins[256 * NB];
    const int t  = threadIdx.x;
    const int n  = blockIdx.x >> 6;
    const int cy = blockIdx.x & 63;
    const int h0 = cy * 8;
    const float* xn = x + (size_t)n * 3 * IMG_H * IMG_W;
#pragma unroll
    for (int b = 0; b < NB; b++) sbins[t * NB + b] = 0.0f;
    for (int r = 0; r < 10; r++) {
        const int h = h0 - 1 + r;
        float g0 = 0.0f, g1 = 0.0f;
        if (h >= 0 && h < IMG_H) {
            const float* p = xn + (size_t)h * IMG_W + 2 * t;
            const float2 a = *(const float2*)(p);
            const float2 b = *(const float2*)(p + IMG_H * IMG_W);
            const float2 c = *(const float2*)(p + 2 * IMG_H * IMG_W);
            g0 = ((a.x + b.x) + c.x) / 3.0f;
            g1 = ((a.y + b.y) + c.y) / 3.0f;
        }
        sgray[r * GSTRIDE + 2 * t + 1] = g0;
        sgray[r * GSTRIDE + 2 * t + 2] = g1;
        if (t < 2) sgray[r * GSTRIDE + t * 513] = 0.0f;
    }
    __syncthreads();
    float* mybins = &sbins[t * NB];
    const int w0 = 2 * t;
    float ra[4], rb[4], rc[4];
#pragma unroll
    for (int i = 0; i < 4; i++) ra[i] = sgray[0 * GSTRIDE + w0 + i];
#pragma unroll
    for (int i = 0; i < 4; i++) rb[i] = sgray[1 * GSTRIDE + w0 + i];
#pragma unroll
    for (int hy = 0; hy < 8; hy++) {
#pragma unroll
        for (int i = 0; i < 4; i++) rc[i] = sgray[(hy + 2) * GSTRIDE + w0 + i];
#pragma unroll
        for (int p = 0; p < 2; p++) {
            const float tl = ra[p], tc = ra[p + 1], tr = ra[p + 2];
            const float ml = rb[p],                 mr = rb[p + 2];
            const float bl = rc[p], bc = rc[p + 1], br = rc[p + 2];
            const float gx = ((((tl - tr) + 2.0f * ml) - 2.0f * mr) + bl) - br;
            const float gy = ((((tl + 2.0f * tc) + tr) - bl) - 2.0f * bc) - br;
            const float nrm = sqrtf(gx * gx + gy * gy);
            const float ph  = (float)atan2((double)gx, (double)gy);
            const float pbf = ph / (float)M_PI * 9.0f;
            int lo = (int)floorf(pbf) % NB; if (lo < 0) lo += NB;
            int hi = (int)ceilf(pbf)  % NB; if (hi < 0) hi += NB;
            atomicAdd(&mybins[lo], nrm);
            atomicAdd(&mybins[hi], 1.0f - nrm);
        }
#pragma unroll
        for (int i = 0; i < 4; i++) { ra[i] = rb[i]; rb[i] = rc[i]; }
    }
    __syncthreads();
    for (int idx = t; idx < NB * 64; idx += 256) {
        const int b  = idx >> 6;
        const int cc = idx & 63;
        const int base = 4 * cc * NB + b;
        const float s = ((sbins[base] + sbins[base + NB])
                         + sbins[base + 2 * NB]) + sbins[base + 3 * NB];
        out[((size_t)n * NB + b) * 4096 + (size_t)cy * 64 + cc] = s * (1.0f / 64.0f);
    }
}

extern "C" void kernel_launch(void* const* d_in, const int* in_sizes, int n_in,
                              void* d_out, int out_size, void* d_ws, size_t ws_size,
                              hipStream_t stream) {
    const float* x = (const float*)d_in[0];
    float* out = (float*)d_out;
    if (ws_size >= (size_t)32 * 262144 * 4) {
        float* g = (float*)d_ws;
        gray_kernel<<<8192, 256, 0, stream>>>(x, g);
        hog2_kernel<<<2048, 256, 0, stream>>>(g, out);
    } else {
        hog_fb_kernel<<<2048, 256, 0, stream>>>(x, out);
    }
}

// Round 6
// 42.395 us; speedup vs baseline: 2.6516x; 1.2534x over previous
//
#include <hip/hip_runtime.h>
#include <math.h>

#define IMG_H 512
#define IMG_W 512
#define NB 9
#define GSTRIDE 516   // 514 used (0..513) + pad

// Fused single kernel. Block = one 8-row band of one image (grid 32x64, 256 thr).
// Staging mirrors the proven hog2 skeleton exactly (unrolled k-loop, float4
// loads, row-level bounds only, t<20 border zeroing) but reads the 3 channel
// planes of x and computes gray = ((c0+c1)+c2)/3.0f into LDS directly --
// eliminating the 70 MB g round-trip and the inter-kernel bubble.
//
// CORRECTNESS MODEL (do not change): decision chain bit-exact vs the fp32 ref:
//   gray  = ((c0+c1)+c2)/3.0f            (IEEE fp32 div)
//   gx,gy = Sobel, tap-lex order, +-1/+-2 (exact multiplies)
//   fast fp32 atan2 classifier; when pb is within 2.5e-4 of an integer
//   (incl. all 0/NaN edge cases) fall back to the exact chain
//   (float)atan2(fp64) -> /(float)pi*9 -> floored mod 9.
__global__ __launch_bounds__(256) void hog_fused_kernel(const float* __restrict__ x,
                                                        float* __restrict__ out) {
    __shared__ float sgray[10 * GSTRIDE];   // 20640 B; reused as reduce buffer

    const int t  = threadIdx.x;
    const int n  = blockIdx.x >> 6;
    const int cy = blockIdx.x & 63;
    const int h0 = cy * 8;
    const float* xn = x + (size_t)n * 3 * IMG_H * IMG_W;

    if (t < 20) sgray[(t >> 1) * GSTRIDE + (t & 1) * 513] = 0.0f;  // borders
#pragma unroll
    for (int k = 0; k < 5; k++) {            // 10 rows x 128 float4
        const int i4 = t + k * 256;
        const int r  = i4 >> 7;
        const int c4 = i4 & 127;
        const int h  = h0 - 1 + r;
        float4 gv = make_float4(0.0f, 0.0f, 0.0f, 0.0f);
        if (h >= 0 && h < IMG_H) {
            const float4* p = (const float4*)(xn + (size_t)h * IMG_W) + c4;
            const float4 a = p[0];
            const float4 b = p[IMG_H * IMG_W / 4];
            const float4 c = p[2 * IMG_H * IMG_W / 4];
            gv.x = ((a.x + b.x) + c.x) / 3.0f;
            gv.y = ((a.y + b.y) + c.y) / 3.0f;
            gv.z = ((a.z + b.z) + c.z) / 3.0f;
            gv.w = ((a.w + b.w) + c.w) / 3.0f;
        }
        float* dst = &sgray[r * GSTRIDE + c4 * 4 + 1];
        dst[0] = gv.x; dst[1] = gv.y; dst[2] = gv.z; dst[3] = gv.w;
    }
    __syncthreads();

    float bins[NB];
#pragma unroll
    for (int b = 0; b < NB; b++) bins[b] = 0.0f;

    const int w0 = 2 * t;
    float ra[4], rb[4], rc[4];
#pragma unroll
    for (int i = 0; i < 4; i++) ra[i] = sgray[0 * GSTRIDE + w0 + i];
#pragma unroll
    for (int i = 0; i < 4; i++) rb[i] = sgray[1 * GSTRIDE + w0 + i];

#pragma unroll
    for (int hy = 0; hy < 8; hy++) {
#pragma unroll
        for (int i = 0; i < 4; i++) rc[i] = sgray[(hy + 2) * GSTRIDE + w0 + i];

#pragma unroll
        for (int p = 0; p < 2; p++) {
            const float tl = ra[p], tc = ra[p + 1], tr = ra[p + 2];
            const float ml = rb[p],                 mr = rb[p + 2];
            const float bl = rc[p], bc = rc[p + 1], br = rc[p + 2];

            const float gx = ((((tl - tr) + 2.0f * ml) - 2.0f * mr) + bl) - br;
            const float gy = ((((tl + 2.0f * tc) + tr) - bl) - 2.0f * bc) - br;
            const float nrm = sqrtf(gx * gx + gy * gy);

            // fast fp32 atan2 classifier
            const float fa = fabsf(gx), fb = fabsf(gy);
            const float mn = fminf(fa, fb), mx = fmaxf(fa, fb);
            float rcpmx;
            asm("v_rcp_f32 %0, %1" : "=v"(rcpmx) : "v"(mx));
            const float tt = mn * rcpmx;            // mx==0 -> NaN -> slow path
            const float ss = tt * tt;
            float po = fmaf(ss, -0.0117212f, 0.05265332f);
            po = fmaf(ss, po, -0.11643287f);
            po = fmaf(ss, po, 0.19354346f);
            po = fmaf(ss, po, -0.33262347f);
            po = fmaf(ss, po, 0.99997726f);
            float th = tt * po;
            if (fa > fb) th = 1.57079632679489662f - th;
            if (gy < 0.0f) th = 3.14159265358979324f - th;
            if (gx < 0.0f) th = -th;
            const float pbh  = th * 2.86478897565412f;   // *9/pi
            const float fl   = floorf(pbh);
            const float frac = pbh - fl;
            const float dist = fminf(frac, 1.0f - frac);

            int lo, hi;
            if (dist > 2.5e-4f) {                   // NaN -> false -> slow
                lo = (int)fl; if (lo < 0) lo += NB;
                hi = lo + 1;  if (hi == NB) hi = 0;
            } else {
                // exact reference chain (bit-identical to rounds 2-5)
                const float ph  = (float)atan2((double)gx, (double)gy);
                const float pbf = ph / (float)M_PI * 9.0f;
                lo = (int)floorf(pbf) % NB; if (lo < 0) lo += NB;
                hi = (int)ceilf(pbf)  % NB; if (hi < 0) hi += NB;
            }

            const float om = 1.0f - nrm;
#pragma unroll
            for (int b = 0; b < NB; b++)
                bins[b] += ((b == lo) ? nrm : 0.0f) + ((b == hi) ? om : 0.0f);
        }
#pragma unroll
        for (int i = 0; i < 4; i++) { ra[i] = rb[i]; rb[i] = rc[i]; }
    }

    __syncthreads();                         // done reading sgray as gray
    float* sred = sgray;                     // alias: 2304 < 5160 floats
#pragma unroll
    for (int b = 0; b < NB; b++) sred[t * NB + b] = bins[b];
    __syncthreads();

    // cell cc gathers threads 4cc..4cc+3 (cols 8cc..8cc+7); fixed order
    for (int idx = t; idx < NB * 64; idx += 256) {
        const int b  = idx >> 6;
        const int cc = idx & 63;
        const int base = 4 * cc * NB + b;
        const float s = ((sred[base] + sred[base + NB])
                         + sred[base + 2 * NB]) + sred[base + 3 * NB];
        out[((size_t)n * NB + b) * 4096 + (size_t)cy * 64 + cc] = s * (1.0f / 64.0f);
    }
}

extern "C" void kernel_launch(void* const* d_in, const int* in_sizes, int n_in,
                              void* d_out, int out_size, void* d_ws, size_t ws_size,
                              hipStream_t stream) {
    const float* x = (const float*)d_in[0];
    float* out = (float*)d_out;
    hog_fused_kernel<<<2048, 256, 0, stream>>>(x, out);
}

// Round 7
// 42.236 us; speedup vs baseline: 2.6616x; 1.0038x over previous
//
#include <hip/hip_runtime.h>
#include <math.h>

#define IMG_H 512
#define IMG_W 512
#define NB 9
#define LSTR 260   // 258 used (0..257) + pad; stride%32=4 spreads rows

// Block = 8-row x 256-col half-band. Grid = 32 images x 64 bands x 2 halves
// = 4096 blocks of 256 threads; thread t owns local col t (8 pixels).
// LDS 10.4 KB -> occupancy wave-capped at 8 blocks/CU = 32 waves (100%).
//
// CORRECTNESS MODEL (do not change): decision chain bit-exact vs the fp32 ref:
//   gray  = ((c0+c1)+c2)/3.0f            (IEEE fp32 div)
//   gx,gy = Sobel, tap-lex order, +-1/+-2 (exact multiplies)
//   fast fp32 atan2 classifier; within 2.5e-4 of integer pb (incl. 0/NaN
//   edge cases) fall back to exact (float)atan2(fp64) -> /(float)pi*9
//   -> floored mod 9.
__global__ __launch_bounds__(256, 8) void hog_kernel(const float* __restrict__ x,
                                                     float* __restrict__ out) {
    __shared__ float sgray[10 * LSTR];   // 10400 B; aliased as reduce buffer

    const int t    = threadIdx.x;
    const int n    = blockIdx.x >> 7;          // 128 blocks per image
    const int r7   = blockIdx.x & 127;
    const int cy   = r7 >> 1;
    const int half = r7 & 1;
    const int h0   = cy * 8;
    const int wstart = half * 256;
    const float* xn = x + (size_t)n * 3 * IMG_H * IMG_W;

    // halo cols (LDS idx 0 and 257) for the 10 rows, by threads 0..19
    if (t < 20) {
        const int r    = t >> 1;
        const int side = t & 1;
        const int h    = h0 - 1 + r;
        const int col  = wstart - 1 + side * 257;
        float g = 0.0f;
        if (h >= 0 && h < IMG_H && col >= 0 && col < IMG_W) {
            const float* p = xn + (size_t)h * IMG_W + col;
            g = ((p[0] + p[IMG_H * IMG_W]) + p[2 * IMG_H * IMG_W]) / 3.0f;
        }
        sgray[r * LSTR + side * 257] = g;
    }
    // interior: 10 rows x 64 float4 (cols wstart..wstart+255 -> idx 1..256)
#pragma unroll
    for (int k = 0; k < 3; k++) {
        const int i4 = t + k * 256;
        if (i4 < 640) {
            const int r  = i4 >> 6;
            const int c4 = i4 & 63;
            const int h  = h0 - 1 + r;
            float4 gv = make_float4(0.0f, 0.0f, 0.0f, 0.0f);
            if (h >= 0 && h < IMG_H) {
                const float* p = xn + (size_t)h * IMG_W + wstart + 4 * c4;
                const float4 a = *(const float4*)(p);
                const float4 b = *(const float4*)(p + IMG_H * IMG_W);
                const float4 c = *(const float4*)(p + 2 * IMG_H * IMG_W);
                gv.x = ((a.x + b.x) + c.x) / 3.0f;
                gv.y = ((a.y + b.y) + c.y) / 3.0f;
                gv.z = ((a.z + b.z) + c.z) / 3.0f;
                gv.w = ((a.w + b.w) + c.w) / 3.0f;
            }
            float* dst = &sgray[r * LSTR + 4 * c4 + 1];
            dst[0] = gv.x; dst[1] = gv.y; dst[2] = gv.z; dst[3] = gv.w;
        }
    }
    __syncthreads();

    float bins[NB];
#pragma unroll
    for (int b = 0; b < NB; b++) bins[b] = 0.0f;

    float ra[3], rb[3], rc[3];
#pragma unroll
    for (int i = 0; i < 3; i++) ra[i] = sgray[0 * LSTR + t + i];
#pragma unroll
    for (int i = 0; i < 3; i++) rb[i] = sgray[1 * LSTR + t + i];

#pragma unroll
    for (int hy = 0; hy < 8; hy++) {
#pragma unroll
        for (int i = 0; i < 3; i++) rc[i] = sgray[(hy + 2) * LSTR + t + i];

        const float tl = ra[0], tc = ra[1], tr = ra[2];
        const float ml = rb[0],             mr = rb[2];
        const float bl = rc[0], bc = rc[1], br = rc[2];

        const float gx = ((((tl - tr) + 2.0f * ml) - 2.0f * mr) + bl) - br;
        const float gy = ((((tl + 2.0f * tc) + tr) - bl) - 2.0f * bc) - br;
        const float nrm = sqrtf(gx * gx + gy * gy);

        // fast fp32 atan2 classifier
        const float fa = fabsf(gx), fb = fabsf(gy);
        const float mn = fminf(fa, fb), mx = fmaxf(fa, fb);
        float rcpmx;
        asm("v_rcp_f32 %0, %1" : "=v"(rcpmx) : "v"(mx));
        const float tt = mn * rcpmx;            // mx==0 -> NaN -> slow path
        const float ss = tt * tt;
        float po = fmaf(ss, -0.0117212f, 0.05265332f);
        po = fmaf(ss, po, -0.11643287f);
        po = fmaf(ss, po, 0.19354346f);
        po = fmaf(ss, po, -0.33262347f);
        po = fmaf(ss, po, 0.99997726f);
        float th = tt * po;
        if (fa > fb) th = 1.57079632679489662f - th;
        if (gy < 0.0f) th = 3.14159265358979324f - th;
        if (gx < 0.0f) th = -th;
        const float pbh  = th * 2.86478897565412f;   // *9/pi
        const float fl   = floorf(pbh);
        const float frac = pbh - fl;
        const float dist = fminf(frac, 1.0f - frac);

        int lo, hi;
        if (dist > 2.5e-4f) {                   // NaN -> false -> slow
            lo = (int)fl; if (lo < 0) lo += NB;
            hi = lo + 1;  if (hi == NB) hi = 0;
        } else {
            // exact reference chain (bit-identical to rounds 2-6)
            const float ph  = (float)atan2((double)gx, (double)gy);
            const float pbf = ph / (float)M_PI * 9.0f;
            lo = (int)floorf(pbf) % NB; if (lo < 0) lo += NB;
            hi = (int)ceilf(pbf)  % NB; if (hi < 0) hi += NB;
        }

        const float om = 1.0f - nrm;
#pragma unroll
        for (int b = 0; b < NB; b++)
            bins[b] += ((b == lo) ? nrm : 0.0f) + ((b == hi) ? om : 0.0f);

#pragma unroll
        for (int i = 0; i < 3; i++) { ra[i] = rb[i]; rb[i] = rc[i]; }
    }

    __syncthreads();                         // done with sgray as gray
    float* sred = sgray;                     // alias: 2304 <= 2600 floats
#pragma unroll
    for (int b = 0; b < NB; b++) sred[t * NB + b] = bins[b];
    __syncthreads();

    // cell cc (local cols 8cc..8cc+7) gathers threads 8cc..8cc+7; fixed order
    for (int idx = t; idx < NB * 32; idx += 256) {
        const int b  = idx >> 5;
        const int cc = idx & 31;
        const int base = 8 * cc * NB + b;
        float s = sred[base];
#pragma unroll
        for (int j = 1; j < 8; j++) s += sred[base + j * NB];
        out[((size_t)n * NB + b) * 4096 + (size_t)cy * 64 + half * 32 + cc]
            = s * (1.0f / 64.0f);
    }
}

extern "C" void kernel_launch(void* const* d_in, const int* in_sizes, int n_in,
                              void* d_out, int out_size, void* d_ws, size_t ws_size,
                              hipStream_t stream) {
    const float* x = (const float*)d_in[0];
    float* out = (float*)d_out;
    hog_kernel<<<4096, 256, 0, stream>>>(x, out);
}

// Round 8
// 40.669 us; speedup vs baseline: 2.7641x; 1.0385x over previous
//
#include <hip/hip_runtime.h>
#include <math.h>

#define IMG_H 512
#define IMG_W 512
#define NB 9
#define LSTR 260   // 256 interior + halo slots 256,257 + pad; stride%32=4

// Block = 8-row x 256-col half-band. Grid = 32 x 64 x 2 = 4096 blocks, 256 thr.
// Thread t owns local col t; processes row pairs (hy, hy+4) -> 2 independent
// dependency chains per wave iteration (ILP). LDS row g holds image row
// h0-1+g: cols at idx 0..255 (ALIGNED float4 writes), left halo at 256,
// right halo at 257.
//
// CORRECTNESS MODEL (do not change): decision chain bit-exact vs the fp32 ref:
//   gray  = ((c0+c1)+c2)/3.0f            (IEEE fp32 div)
//   gx,gy = Sobel, tap-lex order, +-1/+-2 (exact multiplies)
//   fast fp32 atan2 classifier (poly pre-scaled by 9/pi); within 2.5e-4 of
//   integer pb (incl. 0/NaN edges) fall back to exact
//   (float)atan2(fp64) -> /(float)pi*9 -> floored mod 9.
__global__ __launch_bounds__(256, 8) void hog_kernel(const float* __restrict__ x,
                                                     float* __restrict__ out) {
    __shared__ float sgray[10 * LSTR];   // 10400 B; aliased as reduce buffer

    const int t    = threadIdx.x;
    const int n    = blockIdx.x >> 7;          // 128 blocks per image
    const int r7   = blockIdx.x & 127;
    const int cy   = r7 >> 1;
    const int half = r7 & 1;
    const int h0   = cy * 8;
    const int wstart = half * 256;
    const float* xn = x + (size_t)n * 3 * IMG_H * IMG_W;

    // halo cols for the 10 rows (threads 0..19): LDS idx 256 (left), 257 (right)
    if (t < 20) {
        const int r    = t >> 1;
        const int side = t & 1;
        const int h    = h0 - 1 + r;
        const int col  = wstart - 1 + side * 257;
        float g = 0.0f;
        if (h >= 0 && h < IMG_H && col >= 0 && col < IMG_W) {
            const float* p = xn + (size_t)h * IMG_W + col;
            g = ((p[0] + p[IMG_H * IMG_W]) + p[2 * IMG_H * IMG_W]) / 3.0f;
        }
        sgray[r * LSTR + 256 + side] = g;
    }
    // interior: 10 rows x 64 float4, ALIGNED LDS writes (ds_write_b128)
#pragma unroll
    for (int k = 0; k < 3; k++) {
        const int i4 = t + k * 256;
        if (i4 < 640) {
            const int r  = i4 >> 6;
            const int c4 = i4 & 63;
            const int h  = h0 - 1 + r;
            float4 gv = make_float4(0.0f, 0.0f, 0.0f, 0.0f);
            if (h >= 0 && h < IMG_H) {
                const float* p = xn + (size_t)h * IMG_W + wstart + 4 * c4;
                const float4 a = *(const float4*)(p);
                const float4 b = *(const float4*)(p + IMG_H * IMG_W);
                const float4 c = *(const float4*)(p + 2 * IMG_H * IMG_W);
                gv.x = ((a.x + b.x) + c.x) / 3.0f;
                gv.y = ((a.y + b.y) + c.y) / 3.0f;
                gv.z = ((a.z + b.z) + c.z) / 3.0f;
                gv.w = ((a.w + b.w) + c.w) / 3.0f;
            }
            *(float4*)&sgray[r * LSTR + 4 * c4] = gv;
        }
    }
    __syncthreads();

    // window read columns (computed once): t-1, t, t+1 with halo redirect
    const int aL = (t == 0)   ? 256 : (t - 1);
    const int aR = (t == 255) ? 257 : (t + 1);

    float bins[NB];
#pragma unroll
    for (int b = 0; b < NB; b++) bins[b] = 0.0f;

// classify pixel from window rows (RA,RB,RC); yields l, w0, w1
#define PIXEL(RA, RB, RC, L, W0, W1)                                            \
    {                                                                           \
        const float tl = RA[0], tc = RA[1], tr = RA[2];                         \
        const float ml = RB[0],             mr = RB[2];                         \
        const float bl = RC[0], bc = RC[1], br = RC[2];                         \
        const float gx = ((((tl - tr) + 2.0f * ml) - 2.0f * mr) + bl) - br;     \
        const float gy = ((((tl + 2.0f * tc) + tr) - bl) - 2.0f * bc) - br;     \
        const float nrm = sqrtf(gx * gx + gy * gy);                             \
        const float fa = fabsf(gx), fb = fabsf(gy);                             \
        const float mn = fminf(fa, fb), mx = fmaxf(fa, fb);                     \
        float rcpmx;                                                            \
        asm("v_rcp_f32 %0, %1" : "=v"(rcpmx) : "v"(mx));                        \
        const float tt = mn * rcpmx;                                            \
        const float ss = tt * tt;                                               \
        float po = fmaf(ss, -0.03357890f, 0.15084052f);                         \
        po = fmaf(ss, po, -0.33355581f);                                        \
        po = fmaf(ss, po, 0.55446223f);                                         \
        po = fmaf(ss, po, -0.95289958f);                                        \
        po = fmaf(ss, po, 2.86472384f);     /* poly pre-scaled by 9/pi */       \
        float u = tt * po;                  /* pb-units, [0, 2.25] */           \
        if (fa > fb)    u = 4.5f - u;                                           \
        if (gy < 0.0f)  u = 9.0f - u;                                           \
        if (gx < 0.0f)  u = -u;                                                 \
        const float fl   = floorf(u);                                           \
        const float frac = u - fl;                                              \
        const float dist = fminf(frac, 1.0f - frac);                            \
        if (dist > 2.5e-4f) {               /* NaN -> false -> slow */          \
            int lo = (int)fl; if (lo < 0) lo += NB;                             \
            L = lo; W0 = nrm; W1 = 1.0f - nrm;                                  \
        } else {                                                                \
            /* exact reference chain (bit-identical to rounds 2-7) */           \
            const float ph  = (float)atan2((double)gx, (double)gy);             \
            const float pbf = ph / (float)M_PI * 9.0f;                          \
            int lo = (int)floorf(pbf) % NB; if (lo < 0) lo += NB;               \
            int hi = (int)ceilf(pbf)  % NB; if (hi < 0) hi += NB;               \
            L = lo;                                                             \
            if (lo == hi) { W0 = nrm + (1.0f - nrm); W1 = 0.0f; }               \
            else          { W0 = nrm; W1 = 1.0f - nrm; }                        \
        }                                                                       \
    }

    // two rolling windows: chain A = rows 0..3, chain B = rows 4..7
    float raA[3], rbA[3], rcA[3], raB[3], rbB[3], rcB[3];
    {
        const float* r0 = &sgray[0 * LSTR];
        const float* r1 = &sgray[1 * LSTR];
        const float* r4 = &sgray[4 * LSTR];
        const float* r5 = &sgray[5 * LSTR];
        raA[0] = r0[aL]; raA[1] = r0[t]; raA[2] = r0[aR];
        rbA[0] = r1[aL]; rbA[1] = r1[t]; rbA[2] = r1[aR];
        raB[0] = r4[aL]; raB[1] = r4[t]; raB[2] = r4[aR];
        rbB[0] = r5[aL]; rbB[1] = r5[t]; rbB[2] = r5[aR];
    }

#pragma unroll
    for (int k = 0; k < 4; k++) {
        const float* rA = &sgray[(k + 2) * LSTR];
        const float* rB = &sgray[(k + 6) * LSTR];
        rcA[0] = rA[aL]; rcA[1] = rA[t]; rcA[2] = rA[aR];
        rcB[0] = rB[aL]; rcB[1] = rB[t]; rcB[2] = rB[aR];

        int lA, lB; float w0A, w1A, w0B, w1B;
        PIXEL(raA, rbA, rcA, lA, w0A, w1A)
        PIXEL(raB, rbB, rcB, lB, w0B, w1B)

        bool mA[NB], mB[NB];
#pragma unroll
        for (int b = 0; b < NB; b++) { mA[b] = (lA == b); mB[b] = (lB == b); }
#pragma unroll
        for (int b = 0; b < NB; b++) {
            const int bp = (b + 8) % 9;
            bins[b] += (mA[b] ? w0A : (mA[bp] ? w1A : 0.0f))
                     + (mB[b] ? w0B : (mB[bp] ? w1B : 0.0f));
        }

#pragma unroll
        for (int i = 0; i < 3; i++) {
            raA[i] = rbA[i]; rbA[i] = rcA[i];
            raB[i] = rbB[i]; rbB[i] = rcB[i];
        }
    }
#undef PIXEL

    __syncthreads();                         // done with sgray as gray
    float* sred = sgray;                     // alias: 2304 <= 2600 floats
#pragma unroll
    for (int b = 0; b < NB; b++) sred[t * NB + b] = bins[b];
    __syncthreads();

    // cell cc (local cols 8cc..8cc+7) gathers threads 8cc..8cc+7; fixed order
    for (int idx = t; idx < NB * 32; idx += 256) {
        const int b  = idx >> 5;
        const int cc = idx & 31;
        const int base = 8 * cc * NB + b;
        float s = sred[base];
#pragma unroll
        for (int j = 1; j < 8; j++) s += sred[base + j * NB];
        out[((size_t)n * NB + b) * 4096 + (size_t)cy * 64 + half * 32 + cc]
            = s * (1.0f / 64.0f);
    }
}

extern "C" void kernel_launch(void* const* d_in, const int* in_sizes, int n_in,
                              void* d_out, int out_size, void* d_ws, size_t ws_size,
                              hipStream_t stream) {
    const float* x = (const float*)d_in[0];
    float* out = (float*)d_out;
    hog_kernel<<<4096, 256, 0, stream>>>(x, out);
}